// Round 7
// baseline (666.535 us; speedup 1.0000x reference)
//
#include <hip/hip_runtime.h>
#include <hip/hip_bf16.h>

#define NIMG 16
#define IN_CH 512
#define OUT_CH 256
#define HIN 64
#define HOUT 128
#define HP 66  // padded spatial (1-pixel zero halo)

#define WSCALE 0.014731391f      // 1/sqrt(9*512)
#define ACT_GAIN 1.41421356237f  // sqrt(2)
#define CLAMP_V 256.0f

typedef __attribute__((ext_vector_type(8))) short bf16x8;
typedef __attribute__((ext_vector_type(4))) float f32x4;
typedef __attribute__((ext_vector_type(16))) float f32x16;

// Parity tap matrices: G[p][i][a] = u[a-1+2i-p], u = {1,3,3,1}/4 (0 if OOR)
__device__ __constant__ float c_G[2][3][3] = {
    {{0.00f, 0.25f, 0.75f}, {0.75f, 0.75f, 0.25f}, {0.25f, 0.00f, 0.00f}},
    {{0.00f, 0.00f, 0.25f}, {0.25f, 0.75f, 0.75f}, {0.75f, 0.25f, 0.00f}}
};

#define XBF_BYTES ((size_t)NIMG * HP * HP * IN_CH * 2)     // 71,368,704
#define EBF_BYTES ((size_t)9 * 1024 * IN_CH * 2)           //  9,437,184
#define WS_NEED (XBF_BYTES + EBF_BYTES)

// ---------------- x -> padded NHWC bf16 [16][66][66][512] ----------------
__global__ __launch_bounds__(256) void xpose_kernel(const float* __restrict__ x,
                                                    __hip_bfloat16* __restrict__ xbf) {
    const int n = blockIdx.z;
    const int hp = blockIdx.y;        // 0..65
    const int c0 = blockIdx.x << 6;   // 8 chunks of 64 channels
    const int tid = threadIdx.x;
    const size_t obase = ((size_t)n * HP + hp) * HP;  // pixel-row base

    if (hp == 0 || hp == HP - 1) {
        for (int idx = tid; idx < HP * 64; idx += 256) {
            int wp = idx >> 6, c = idx & 63;
            xbf[(obase + wp) * IN_CH + c0 + c] = __float2bfloat16(0.f);
        }
        return;
    }
    __shared__ float tile[64][65];
    {
        int cc = tid >> 6, w = tid & 63;
        for (int cb = 0; cb < 64; cb += 4)
            tile[cb + cc][w] =
                x[(((size_t)n * IN_CH + c0 + cb + cc) * HIN + (hp - 1)) * HIN + w];
    }
    __syncthreads();
    {
        int c = tid & 63, wg = tid >> 6;
        for (int wb = 0; wb < 64; wb += 4) {
            int w2 = wb + wg;
            xbf[(obase + (w2 + 1)) * IN_CH + c0 + c] = __float2bfloat16(tile[c][w2]);
        }
        if (tid < 128) {
            int which = tid >> 6, c2 = tid & 63;
            xbf[(obase + (which ? (HP - 1) : 0)) * IN_CH + c0 + c2] = __float2bfloat16(0.f);
        }
    }
}

// ---------------- w -> E bf16 [9(tap)][1024(oc*4+par)][512(c)] ----------------
__global__ __launch_bounds__(256) void build_ebf_kernel(const float* __restrict__ w,
                                                        __hip_bfloat16* __restrict__ ebf) {
    int gid = blockIdx.x * 256 + threadIdx.x;  // oc*512 + c
    if (gid >= OUT_CH * IN_CH) return;
    int oc = gid >> 9, c = gid & 511;
    float wm[3][3];
    const float* wp = w + (size_t)gid * 9;
#pragma unroll
    for (int a = 0; a < 3; ++a)
#pragma unroll
        for (int b = 0; b < 3; ++b) wm[a][b] = wp[a * 3 + b] * WSCALE;
#pragma unroll
    for (int i = 0; i < 3; ++i)
#pragma unroll
        for (int j = 0; j < 3; ++j)
#pragma unroll
            for (int pu = 0; pu < 2; ++pu)
#pragma unroll
                for (int pv = 0; pv < 2; ++pv) {
                    float s = 0.f;
#pragma unroll
                    for (int a = 0; a < 3; ++a)
#pragma unroll
                        for (int b = 0; b < 3; ++b)
                            s += wm[a][b] * c_G[pu][i][a] * c_G[pv][j][b];
                    ebf[((size_t)(i * 3 + j) * 1024 + oc * 4 + pu * 2 + pv) * IN_CH + c] =
                        __float2bfloat16(s);
                }
}

// 8 MFMAs of 32x32x16: AF[mt2*2+ks], BF[nt*2+ks]; acc[MH*4 + mt2*2 + nt].
// ks0 quad first, then ks1 quad (dependent pairs 4 apart).
#define MFMA8(AF, BF, MH)                                                                   \
    do {                                                                                    \
        acc[(MH)*4+0] = __builtin_amdgcn_mfma_f32_32x32x16_bf16((AF)[0], (BF)[0], acc[(MH)*4+0], 0, 0, 0); \
        acc[(MH)*4+1] = __builtin_amdgcn_mfma_f32_32x32x16_bf16((AF)[0], (BF)[2], acc[(MH)*4+1], 0, 0, 0); \
        acc[(MH)*4+2] = __builtin_amdgcn_mfma_f32_32x32x16_bf16((AF)[2], (BF)[0], acc[(MH)*4+2], 0, 0, 0); \
        acc[(MH)*4+3] = __builtin_amdgcn_mfma_f32_32x32x16_bf16((AF)[2], (BF)[2], acc[(MH)*4+3], 0, 0, 0); \
        acc[(MH)*4+0] = __builtin_amdgcn_mfma_f32_32x32x16_bf16((AF)[1], (BF)[1], acc[(MH)*4+0], 0, 0, 0); \
        acc[(MH)*4+1] = __builtin_amdgcn_mfma_f32_32x32x16_bf16((AF)[1], (BF)[3], acc[(MH)*4+1], 0, 0, 0); \
        acc[(MH)*4+2] = __builtin_amdgcn_mfma_f32_32x32x16_bf16((AF)[3], (BF)[1], acc[(MH)*4+2], 0, 0, 0); \
        acc[(MH)*4+3] = __builtin_amdgcn_mfma_f32_32x32x16_bf16((AF)[3], (BF)[3], acc[(MH)*4+3], 0, 0, 0); \
    } while (0)

// staging byte constants
#define CJA_B 540672   // +8 rows of padded image: 8*66*512*2
#define CJB_B 131072   // +128 rows of E: 128*512*2
// LDS dst slot constants (bytes), PAR literal
#define DAK1(PAR) (((((PAR) ^ 1) << 2) | 1) << 14)
#define DBK1(PAR) (((((PAR) ^ 1) << 2) | 3) << 14)
#define DAK0(PAR) ((((PAR) << 2) | 0) << 14)
#define DBK0(PAR) ((((PAR) << 2) | 2) << 14)

#define GLL(SRC, DSTOFF)                                                          \
    __builtin_amdgcn_global_load_lds(                                             \
        (const __attribute__((address_space(1))) unsigned int*)(SRC),             \
        (__attribute__((address_space(3))) unsigned int*)(ldsW + (DSTOFF)), 16, 0, 0)

// One K-tile (BK=64), 4 phases, PAR = tile parity LITERAL.
// Schedule/ledger identical to R6 (lgkm 4/8/4/8, vmcnt at p0/p2, 1 barrier/phase);
// reads are ds_read_b128 at immediate offsets off 8 invariant int LDS offsets;
// staging via uniform scalar byte offsets (sA1/sA0/sB1/sB0) + per-lane voffA/voffB.
#define TILE_ITER(PAR, TT, SP01, SP23, VMS, LGK3, LAST)                           \
    {                                                                             \
        const int a0 = (PAR) ? aOffO0 : aOffE0;                                   \
        const int a1 = (PAR) ? aOffO1 : aOffE1;                                   \
        const int c0 = (PAR) ? bOffO0 : bOffE0;                                   \
        const int c1 = (PAR) ? bOffO1 : bOffE1;                                   \
        /* ---- p0: compute (kh0,mh0) afE,b0; prefetch afO<-(kh0,mh1); stage AK1 */\
        afO[0] = *(const bf16x8*)&lds[a0 + 4096];                                 \
        afO[1] = *(const bf16x8*)&lds[a1 + 4096];                                 \
        afO[2] = *(const bf16x8*)&lds[a0 + 4096 + 2048];                          \
        afO[3] = *(const bf16x8*)&lds[a1 + 4096 + 2048];                          \
        if (SP01) { GLL(xbc + sA1 + voffA, DAK1(PAR));                            \
                    GLL(xbc + sA1 + voffA + CJA_B, DAK1(PAR) + 8192); }           \
        sA1 += ((TT) == 22 || (TT) == 46) ? 64640 : 128;                          \
        asm volatile("s_waitcnt lgkmcnt(4)" ::: "memory");                        \
        __builtin_amdgcn_sched_barrier(0);                                        \
        __builtin_amdgcn_s_setprio(1);                                            \
        MFMA8(afE, b0, 0);                                                        \
        __builtin_amdgcn_s_setprio(0);                                            \
        asm volatile("s_waitcnt " VMS ::: "memory");                              \
        __builtin_amdgcn_s_barrier();                                             \
        __builtin_amdgcn_sched_barrier(0);                                        \
        /* ---- p1: compute (kh0,mh1) afO,b0; prefetch afE<-(kh1,mh0)+b1; BK1 */  \
        afE[0] = *(const bf16x8*)&lds[a0 + 16384];                                \
        afE[1] = *(const bf16x8*)&lds[a1 + 16384];                                \
        afE[2] = *(const bf16x8*)&lds[a0 + 16384 + 2048];                         \
        afE[3] = *(const bf16x8*)&lds[a1 + 16384 + 2048];                         \
        b1[0] = *(const bf16x8*)&lds[c0 + 16384];                                 \
        b1[1] = *(const bf16x8*)&lds[c1 + 16384];                                 \
        b1[2] = *(const bf16x8*)&lds[c0 + 16384 + 2048];                          \
        b1[3] = *(const bf16x8*)&lds[c1 + 16384 + 2048];                          \
        if (SP01) { GLL(ebc + sB1 + voffB, DBK1(PAR));                            \
                    GLL(ebc + sB1 + voffB + CJB_B, DBK1(PAR) + 8192); }           \
        sB1 += (((TT) & 7) == 6) ? 1047680 : 128;                                 \
        asm volatile("s_waitcnt lgkmcnt(8)" ::: "memory");                        \
        __builtin_amdgcn_sched_barrier(0);                                        \
        __builtin_amdgcn_s_setprio(1);                                            \
        MFMA8(afO, b0, 1);                                                        \
        __builtin_amdgcn_s_setprio(0);                                            \
        __builtin_amdgcn_s_barrier();                                             \
        __builtin_amdgcn_sched_barrier(0);                                        \
        /* ---- p2: compute (kh1,mh0) afE,b1; prefetch afO<-(kh1,mh1); stage AK0 */\
        afO[0] = *(const bf16x8*)&lds[a0 + 16384 + 4096];                         \
        afO[1] = *(const bf16x8*)&lds[a1 + 16384 + 4096];                         \
        afO[2] = *(const bf16x8*)&lds[a0 + 16384 + 4096 + 2048];                  \
        afO[3] = *(const bf16x8*)&lds[a1 + 16384 + 4096 + 2048];                  \
        if (SP23) { GLL(xbc + sA0 + voffA, DAK0(PAR));                            \
                    GLL(xbc + sA0 + voffA + CJA_B, DAK0(PAR) + 8192); }           \
        sA0 += ((TT) == 21 || (TT) == 45) ? 64640 : 128;                          \
        asm volatile("s_waitcnt lgkmcnt(4)" ::: "memory");                        \
        __builtin_amdgcn_sched_barrier(0);                                        \
        __builtin_amdgcn_s_setprio(1);                                            \
        MFMA8(afE, b1, 0);                                                        \
        __builtin_amdgcn_s_setprio(0);                                            \
        asm volatile("s_waitcnt " VMS ::: "memory");                              \
        __builtin_amdgcn_s_barrier();                                             \
        __builtin_amdgcn_sched_barrier(0);                                        \
        /* ---- p3: compute (kh1,mh1) afO,b1; prefetch next tile afE,b0; BK0 */   \
        if (!(LAST)) {                                                            \
            const int na0 = (PAR) ? aOffE0 : aOffO0;                              \
            const int na1 = (PAR) ? aOffE1 : aOffO1;                              \
            const int nc0 = (PAR) ? bOffE0 : bOffO0;                              \
            const int nc1 = (PAR) ? bOffE1 : bOffO1;                              \
            afE[0] = *(const bf16x8*)&lds[na0];                                   \
            afE[1] = *(const bf16x8*)&lds[na1];                                   \
            afE[2] = *(const bf16x8*)&lds[na0 + 2048];                            \
            afE[3] = *(const bf16x8*)&lds[na1 + 2048];                            \
            b0[0] = *(const bf16x8*)&lds[nc0];                                    \
            b0[1] = *(const bf16x8*)&lds[nc1];                                    \
            b0[2] = *(const bf16x8*)&lds[nc0 + 2048];                             \
            b0[3] = *(const bf16x8*)&lds[nc1 + 2048];                             \
        }                                                                         \
        if (SP23) { GLL(ebc + sB0 + voffB, DBK0(PAR));                            \
                    GLL(ebc + sB0 + voffB + CJB_B, DBK0(PAR) + 8192); }           \
        sB0 += (((TT) & 7) == 5) ? 1047680 : 128;                                 \
        asm volatile("s_waitcnt " LGK3 ::: "memory");                             \
        __builtin_amdgcn_sched_barrier(0);                                        \
        __builtin_amdgcn_s_setprio(1);                                            \
        MFMA8(afO, b1, 1);                                                        \
        __builtin_amdgcn_s_setprio(0);                                            \
        __builtin_amdgcn_s_barrier();                                             \
        __builtin_amdgcn_sched_barrier(0);                                        \
    }

// ---------------- 256x256 pipelined 32x32x16-MFMA implicit-GEMM conv ----------------
__global__ __launch_bounds__(512, 2) void mfma_conv8_kernel(
    const __hip_bfloat16* __restrict__ xbf, const __hip_bfloat16* __restrict__ ebf,
    const float* __restrict__ bias, float* __restrict__ out) {
    __shared__ __align__(16) char lds[131072];

    const int tid = threadIdx.x;
    const int lane = tid & 63;
    const int wid = tid >> 6;      // 0..7
    const int wy = wid >> 2;       // 0..1 : M half (128 rows)
    const int wx = wid & 3;        // 0..3 : N quarter (64 cols)

    const int bid = blockIdx.x;
    const int wkid = ((bid & 7) << 7) + (bid >> 3);
    const int mtile = wkid >> 2;
    const int ntile = wkid & 3;
    const int n = mtile >> 4;
    const int sub = mtile & 15;
    const int qh0 = (sub >> 2) << 4;
    const int qw0 = (sub & 3) << 4;
    const int n0 = ntile << 8;

    const int qc_s = lane >> 2;
    const int src_slot = (((lane & 3) ^ ((lane >> 3) & 3)) << 3);  // write-side 2-bit key

    f32x16 acc[8];
#pragma unroll
    for (int j = 0; j < 8; ++j) acc[j] = (f32x16)(0.f);

    char* ldsW = lds + (wid << 10);
    const char* xbc = (const char*)xbf;
    const char* ebc = (const char*)ebf;

    // prologue-only generic stage (full address computation; runs 6 times)
    auto stage = [&](int s) {
        const int tt2 = s >> 2;
        const int part = s & 3;
        const int mat = part & 1;
        const int kh = part >> 1;
        const int tap = tt2 >> 3;
        const int chan = ((tt2 & 7) << 6) + (kh << 5) + src_slot;
        char* dst = lds + ((((tt2 & 1) << 2) | (mat << 1) | kh) << 14) + (wid << 10);
        if (mat == 0) {
            const int fi = (tap * 171) >> 9;
            const int fj = tap - fi * 3;
            const int wp = qw0 + fj + qc_s;
#pragma unroll
            for (int c = 0; c < 2; ++c) {
                const int hp = qh0 + fi + (c << 3) + wid;
                const __hip_bfloat16* src =
                    xbf + (((size_t)n * HP + hp) * HP + wp) * IN_CH + chan;
                __builtin_amdgcn_global_load_lds(
                    (const __attribute__((address_space(1))) unsigned int*)src,
                    (__attribute__((address_space(3))) unsigned int*)(dst + (c << 13)),
                    16, 0, 0);
            }
        } else {
#pragma unroll
            for (int c = 0; c < 2; ++c) {
                const int r = (c << 7) + (wid << 4) + qc_s;
                const __hip_bfloat16* src =
                    ebf + ((size_t)tap * 1024 + n0 + r) * IN_CH + chan;
                __builtin_amdgcn_global_load_lds(
                    (const __attribute__((address_space(1))) unsigned int*)src,
                    (__attribute__((address_space(3))) unsigned int*)(dst + (c << 13)),
                    16, 0, 0);
            }
        }
    };

    // read-side bases: key = (row>>1)&3 (invariant to mt/nt row steps of 32 and wy/wx)
    const int key = (lane >> 1) & 3;
    const int sl = lane >> 5;
    const int arow = ((wy << 7) + (lane & 31)) * 64;
    const int aOffE0 = arow + ((sl ^ key) << 4);
    const int aOffE1 = arow + (((sl | 2) ^ key) << 4);
    const int aOffO0 = aOffE0 + 65536;
    const int aOffO1 = aOffE1 + 65536;
    const int brow = 32768 + ((wx << 6) + (lane & 31)) * 64;
    const int bOffE0 = brow + ((sl ^ key) << 4);
    const int bOffE1 = brow + (((sl | 2) ^ key) << 4);
    const int bOffO0 = bOffE0 + 65536;
    const int bOffO1 = bOffE1 + 65536;

    // staging: uniform scalar byte offsets + per-lane 32-bit voffsets
    const int voffA = ((((n * HP + qh0 + wid) * HP + qw0 + qc_s) * IN_CH) + src_slot) * 2;
    const int voffB = (((n0 + (wid << 4) + qc_s) * IN_CH) + src_slot) * 2;
    int sA1 = 192, sA0 = 256, sB1 = 192, sB0 = 256;  // bytes (96/128 elements)

    // ---- prologue: items 0..5; confirm items 0,1; read phase-0 frags ----
#pragma unroll
    for (int s = 0; s < 6; ++s) stage(s);
    asm volatile("s_waitcnt vmcnt(8)" ::: "memory");
    __builtin_amdgcn_s_barrier();
    __builtin_amdgcn_sched_barrier(0);

    bf16x8 afE[4], afO[4], b0[4], b1[4];
    afE[0] = *(const bf16x8*)&lds[aOffE0];
    afE[1] = *(const bf16x8*)&lds[aOffE1];
    afE[2] = *(const bf16x8*)&lds[aOffE0 + 2048];
    afE[3] = *(const bf16x8*)&lds[aOffE1 + 2048];
    b0[0] = *(const bf16x8*)&lds[bOffE0];
    b0[1] = *(const bf16x8*)&lds[bOffE1];
    b0[2] = *(const bf16x8*)&lds[bOffE0 + 2048];
    b0[3] = *(const bf16x8*)&lds[bOffE1 + 2048];

    // ---- main loop: tiles 0..67, then peeled tail 68..71 ----
#pragma unroll 1
    for (int tt = 0; tt < 68; tt += 2) {
        TILE_ITER(0, tt, 1, 1, "vmcnt(6)", "lgkmcnt(8)", 0);
        TILE_ITER(1, tt + 1, 1, 1, "vmcnt(6)", "lgkmcnt(8)", 0);
    }
    TILE_ITER(0, 68, 1, 1, "vmcnt(6)", "lgkmcnt(8)", 0);
    TILE_ITER(1, 69, 1, 1, "vmcnt(0)", "lgkmcnt(8)", 0);
    TILE_ITER(0, 70, 1, 0, "vmcnt(0)", "lgkmcnt(8)", 0);
    TILE_ITER(1, 71, 0, 0, "vmcnt(0)", "lgkmcnt(0)", 1);

    // ---- epilogue: bias + leaky-relu*sqrt2 + clamp, scatter to NCHW ----
    // C layout (m74/m101): col = lane&31, row = (reg&3) + 8*(reg>>2) + 4*(lane>>5)
    float bv[2];
#pragma unroll
    for (int nt = 0; nt < 2; ++nt)
        bv[nt] = bias[(n0 + (wx << 6) + (nt << 5) + (lane & 31)) >> 2];
#pragma unroll
    for (int j = 0; j < 8; ++j) {
        const int mt = j >> 1, nt = j & 1;
        const int nn = n0 + (wx << 6) + (nt << 5) + (lane & 31);
        const int oc = nn >> 2, pu = (nn >> 1) & 1, pv = nn & 1;
#pragma unroll
        for (int v = 0; v < 16; ++v) {
            const int m = (wy << 7) + (mt << 5) + (v & 3) + ((v >> 2) << 3) + (sl << 2);
            const int qr = m >> 4, qc = m & 15;
            const int hb = 2 * (qh0 + qr), wb = 2 * (qw0 + qc);
            float val = acc[j][v] + bv[nt];
            val = (val >= 0.f ? val : 0.2f * val) * ACT_GAIN;
            val = fminf(fmaxf(val, -CLAMP_V), CLAMP_V);
            out[(((size_t)n * OUT_CH + oc) * HOUT + (hb + pu)) * HOUT + (wb + pv)] = val;
        }
    }
}

// ---------------- fallback (R1 proven path) if workspace too small ----------------
__global__ void build_e_kernel(const float* __restrict__ w, float* __restrict__ e_ws) {
    int gid = blockIdx.x * blockDim.x + threadIdx.x;
    if (gid >= OUT_CH * IN_CH) return;
    float wm[3][3];
    const float* wp = w + (size_t)gid * 9;
#pragma unroll
    for (int a = 0; a < 3; ++a)
#pragma unroll
        for (int b = 0; b < 3; ++b) wm[a][b] = wp[a * 3 + b] * WSCALE;
    float* op = e_ws + (size_t)gid * 36;
#pragma unroll
    for (int i = 0; i < 3; ++i)
#pragma unroll
        for (int j = 0; j < 3; ++j)
#pragma unroll
            for (int pu = 0; pu < 2; ++pu)
#pragma unroll
                for (int pv = 0; pv < 2; ++pv) {
                    float s = 0.f;
#pragma unroll
                    for (int a = 0; a < 3; ++a)
#pragma unroll
                        for (int b = 0; b < 3; ++b)
                            s += wm[a][b] * c_G[pu][i][a] * c_G[pv][j][b];
                    op[(i * 3 + j) * 4 + pu * 2 + pv] = s;
                }
}

#define OGB 8
#define CB 8
#define QT 16
__global__ __launch_bounds__(256) void fused_conv_kernel(
    const float* __restrict__ x, const float* __restrict__ e_ws,
    const float* __restrict__ bias, float* __restrict__ out) {
    __shared__ float sX[CB][18][19];
    __shared__ float4 sE[OGB * CB * 9];
    const int tid = threadIdx.x;
    const int o2 = tid >> 7;
    const int qy = (tid >> 3) & 15;
    const int qxp = tid & 7;
    const int tileIdx = blockIdx.x;
    const int hq0 = (tileIdx >> 2) * QT;
    const int wq0 = (tileIdx & 3) * QT;
    const int o0 = blockIdx.y * OGB;
    const int n = blockIdx.z;
    float4 acc[2][4];
#pragma unroll
    for (int q = 0; q < 2; ++q)
#pragma unroll
        for (int oo = 0; oo < 4; ++oo) acc[q][oo] = make_float4(0.f, 0.f, 0.f, 0.f);
    for (int c0 = 0; c0 < IN_CH; c0 += CB) {
        for (int idx = tid; idx < CB * 18 * 18; idx += 256) {
            int cc = idx / 324;
            int rem = idx - cc * 324;
            int r = rem / 18;
            int col = rem - r * 18;
            int h = hq0 - 1 + r;
            int ww = wq0 - 1 + col;
            float v = 0.f;
            if (h >= 0 && h < HIN && ww >= 0 && ww < HIN)
                v = x[(((size_t)n * IN_CH + (c0 + cc)) * HIN + h) * HIN + ww];
            sX[cc][r][col] = v;
        }
        {
            float* sEf = (float*)sE;
            for (int idx = tid; idx < OGB * CB * 36; idx += 256) {
                int ol = idx / (CB * 36);
                int rem = idx - ol * (CB * 36);
                sEf[ol * (CB * 36) + rem] =
                    e_ws[((size_t)(o0 + ol) * IN_CH + c0) * 36 + rem];
            }
        }
        __syncthreads();
#pragma unroll 1
        for (int cc = 0; cc < CB; ++cc) {
#pragma unroll
            for (int i = 0; i < 3; ++i) {
#pragma unroll
                for (int j = 0; j < 3; ++j) {
                    float xv0 = sX[cc][qy + i][2 * qxp + j];
                    float xv1 = sX[cc][qy + i][2 * qxp + 1 + j];
#pragma unroll
                    for (int oo = 0; oo < 4; ++oo) {
                        float4 e = sE[((o2 * 4 + oo) * CB + cc) * 9 + i * 3 + j];
                        acc[0][oo].x += xv0 * e.x; acc[0][oo].y += xv0 * e.y;
                        acc[0][oo].z += xv0 * e.z; acc[0][oo].w += xv0 * e.w;
                        acc[1][oo].x += xv1 * e.x; acc[1][oo].y += xv1 * e.y;
                        acc[1][oo].z += xv1 * e.z; acc[1][oo].w += xv1 * e.w;
                    }
                }
            }
        }
        __syncthreads();
    }
#pragma unroll
    for (int q = 0; q < 2; ++q) {
        int qx = 2 * qxp + q;
        int u0 = 2 * (hq0 + qy);
        int v0 = 2 * (wq0 + qx);
#pragma unroll
        for (int oo = 0; oo < 4; ++oo) {
            int o = o0 + o2 * 4 + oo;
            float b = bias[o];
            float vals[4] = {acc[q][oo].x, acc[q][oo].y, acc[q][oo].z, acc[q][oo].w};
#pragma unroll
            for (int p = 0; p < 4; ++p) {
                int pu = p >> 1, pv = p & 1;
                float v = vals[p] + b;
                v = (v >= 0.f ? v : 0.2f * v) * ACT_GAIN;
                v = fminf(fmaxf(v, -CLAMP_V), CLAMP_V);
                out[(((size_t)n * OUT_CH + o) * HOUT + (u0 + pu)) * HOUT + (v0 + pv)] = v;
            }
        }
    }
}

extern "C" void kernel_launch(void* const* d_in, const int* in_sizes, int n_in,
                              void* d_out, int out_size, void* d_ws, size_t ws_size,
                              hipStream_t stream) {
    const float* x = (const float*)d_in[0];
    const float* w = (const float*)d_in[1];
    const float* bias = (const float*)d_in[2];
    float* out = (float*)d_out;

    if (ws_size >= WS_NEED) {
        __hip_bfloat16* xbf = (__hip_bfloat16*)d_ws;
        __hip_bfloat16* ebf = (__hip_bfloat16*)((char*)d_ws + XBF_BYTES);
        xpose_kernel<<<dim3(8, HP, NIMG), 256, 0, stream>>>(x, xbf);
        build_ebf_kernel<<<(OUT_CH * IN_CH + 255) / 256, 256, 0, stream>>>(w, ebf);
        mfma_conv8_kernel<<<dim3(1024), 512, 0, stream>>>(xbf, ebf, bias, out);
    } else {
        float* e_ws = (float*)d_ws;
        build_e_kernel<<<(OUT_CH * IN_CH + 255) / 256, 256, 0, stream>>>(w, e_ws);
        dim3 grid(16, OUT_CH / OGB, NIMG);
        fused_conv_kernel<<<grid, 256, 0, stream>>>(x, e_ws, bias, out);
    }
}

// Round 8
// 664.333 us; speedup vs baseline: 1.0033x; 1.0033x over previous
//
#include <hip/hip_runtime.h>
#include <hip/hip_bf16.h>

#define NIMG 16
#define IN_CH 512
#define OUT_CH 256
#define HIN 64
#define HOUT 128
#define HP 66  // padded spatial (1-pixel zero halo)

#define WSCALE 0.014731391f      // 1/sqrt(9*512)
#define ACT_GAIN 1.41421356237f  // sqrt(2)
#define CLAMP_V 256.0f

typedef __attribute__((ext_vector_type(8))) short bf16x8;
typedef __attribute__((ext_vector_type(4))) float f32x4;
typedef __attribute__((ext_vector_type(16))) float f32x16;

// Parity tap matrices: G[p][i][a] = u[a-1+2i-p], u = {1,3,3,1}/4 (0 if OOR)
__device__ __constant__ float c_G[2][3][3] = {
    {{0.00f, 0.25f, 0.75f}, {0.75f, 0.75f, 0.25f}, {0.25f, 0.00f, 0.00f}},
    {{0.00f, 0.00f, 0.25f}, {0.25f, 0.75f, 0.75f}, {0.75f, 0.25f, 0.00f}}
};

#define XBF_BYTES ((size_t)NIMG * HP * HP * IN_CH * 2)     // 71,368,704
#define EBF_BYTES ((size_t)9 * 1024 * IN_CH * 2)           //  9,437,184
#define WS_NEED (XBF_BYTES + EBF_BYTES)

// ---------------- x -> padded NHWC bf16 [16][66][66][512] ----------------
__global__ __launch_bounds__(256) void xpose_kernel(const float* __restrict__ x,
                                                    __hip_bfloat16* __restrict__ xbf) {
    const int n = blockIdx.z;
    const int hp = blockIdx.y;        // 0..65
    const int c0 = blockIdx.x << 6;   // 8 chunks of 64 channels
    const int tid = threadIdx.x;
    const size_t obase = ((size_t)n * HP + hp) * HP;  // pixel-row base

    if (hp == 0 || hp == HP - 1) {
        for (int idx = tid; idx < HP * 64; idx += 256) {
            int wp = idx >> 6, c = idx & 63;
            xbf[(obase + wp) * IN_CH + c0 + c] = __float2bfloat16(0.f);
        }
        return;
    }
    __shared__ float tile[64][65];
    {
        int cc = tid >> 6, w = tid & 63;
        for (int cb = 0; cb < 64; cb += 4)
            tile[cb + cc][w] =
                x[(((size_t)n * IN_CH + c0 + cb + cc) * HIN + (hp - 1)) * HIN + w];
    }
    __syncthreads();
    {
        int c = tid & 63, wg = tid >> 6;
        for (int wb = 0; wb < 64; wb += 4) {
            int w2 = wb + wg;
            xbf[(obase + (w2 + 1)) * IN_CH + c0 + c] = __float2bfloat16(tile[c][w2]);
        }
        if (tid < 128) {
            int which = tid >> 6, c2 = tid & 63;
            xbf[(obase + (which ? (HP - 1) : 0)) * IN_CH + c0 + c2] = __float2bfloat16(0.f);
        }
    }
}

// ---------------- w -> E bf16 [9(tap)][1024(oc*4+par)][512(c)] ----------------
__global__ __launch_bounds__(256) void build_ebf_kernel(const float* __restrict__ w,
                                                        __hip_bfloat16* __restrict__ ebf) {
    int gid = blockIdx.x * 256 + threadIdx.x;  // oc*512 + c
    if (gid >= OUT_CH * IN_CH) return;
    int oc = gid >> 9, c = gid & 511;
    float wm[3][3];
    const float* wp = w + (size_t)gid * 9;
#pragma unroll
    for (int a = 0; a < 3; ++a)
#pragma unroll
        for (int b = 0; b < 3; ++b) wm[a][b] = wp[a * 3 + b] * WSCALE;
#pragma unroll
    for (int i = 0; i < 3; ++i)
#pragma unroll
        for (int j = 0; j < 3; ++j)
#pragma unroll
            for (int pu = 0; pu < 2; ++pu)
#pragma unroll
                for (int pv = 0; pv < 2; ++pv) {
                    float s = 0.f;
#pragma unroll
                    for (int a = 0; a < 3; ++a)
#pragma unroll
                        for (int b = 0; b < 3; ++b)
                            s += wm[a][b] * c_G[pu][i][a] * c_G[pv][j][b];
                    ebf[((size_t)(i * 3 + j) * 1024 + oc * 4 + pu * 2 + pv) * IN_CH + c] =
                        __float2bfloat16(s);
                }
}

// 8 MFMAs of 32x32x16: AF[mt2*2+ks], BF[nt*2+ks]; acc[MH*4 + mt2*2 + nt].
// ks0 quad first, then ks1 quad (dependent pairs 4 apart).
#define MFMA8(AF, BF, MH)                                                                   \
    do {                                                                                    \
        acc[(MH)*4+0] = __builtin_amdgcn_mfma_f32_32x32x16_bf16((AF)[0], (BF)[0], acc[(MH)*4+0], 0, 0, 0); \
        acc[(MH)*4+1] = __builtin_amdgcn_mfma_f32_32x32x16_bf16((AF)[0], (BF)[2], acc[(MH)*4+1], 0, 0, 0); \
        acc[(MH)*4+2] = __builtin_amdgcn_mfma_f32_32x32x16_bf16((AF)[2], (BF)[0], acc[(MH)*4+2], 0, 0, 0); \
        acc[(MH)*4+3] = __builtin_amdgcn_mfma_f32_32x32x16_bf16((AF)[2], (BF)[2], acc[(MH)*4+3], 0, 0, 0); \
        acc[(MH)*4+0] = __builtin_amdgcn_mfma_f32_32x32x16_bf16((AF)[1], (BF)[1], acc[(MH)*4+0], 0, 0, 0); \
        acc[(MH)*4+1] = __builtin_amdgcn_mfma_f32_32x32x16_bf16((AF)[1], (BF)[3], acc[(MH)*4+1], 0, 0, 0); \
        acc[(MH)*4+2] = __builtin_amdgcn_mfma_f32_32x32x16_bf16((AF)[3], (BF)[1], acc[(MH)*4+2], 0, 0, 0); \
        acc[(MH)*4+3] = __builtin_amdgcn_mfma_f32_32x32x16_bf16((AF)[3], (BF)[3], acc[(MH)*4+3], 0, 0, 0); \
    } while (0)

// staging byte constants
#define CJA_B 540672   // +8 rows of padded image: 8*66*512*2
#define CJB_B 131072   // +128 rows of E: 128*512*2
// LDS dst slot constants (bytes), PAR literal
#define DAK1(PAR) (((((PAR) ^ 1) << 2) | 1) << 14)
#define DBK1(PAR) (((((PAR) ^ 1) << 2) | 3) << 14)
#define DAK0(PAR) ((((PAR) << 2) | 0) << 14)
#define DBK0(PAR) ((((PAR) << 2) | 2) << 14)

#define GLL(SRC, DSTOFF)                                                          \
    __builtin_amdgcn_global_load_lds(                                             \
        (const __attribute__((address_space(1))) unsigned int*)(SRC),             \
        (__attribute__((address_space(3))) unsigned int*)(ldsW + (DSTOFF)), 16, 0, 0)

// One K-tile (BK=64), 4 phases, PAR = tile parity LITERAL.
// Schedule/ledger identical to R6 (lgkm 4/8/4/8, vmcnt at p0/p2, 1 barrier/phase).
// LDS swizzle wkey(row) = r2 + 2*r1 (bit-SWAPPED vs R7): read bank-group
// g = 4*l0 + 2*l1 + (l5^l2) is bijective in (l0,l1,l5) per 8-lane service set
// {quad q lower half + quad q upper half} - the grouping law fitted to R3/R4/R6/R7.
#define TILE_ITER(PAR, TT, SP01, SP23, VMS, LGK3, LAST)                           \
    {                                                                             \
        const int a0 = (PAR) ? aOffO0 : aOffE0;                                   \
        const int a1 = (PAR) ? aOffO1 : aOffE1;                                   \
        const int c0 = (PAR) ? bOffO0 : bOffE0;                                   \
        const int c1 = (PAR) ? bOffO1 : bOffE1;                                   \
        /* ---- p0: compute (kh0,mh0) afE,b0; prefetch afO<-(kh0,mh1); stage AK1 */\
        afO[0] = *(const bf16x8*)&lds[a0 + 4096];                                 \
        afO[1] = *(const bf16x8*)&lds[a1 + 4096];                                 \
        afO[2] = *(const bf16x8*)&lds[a0 + 4096 + 2048];                          \
        afO[3] = *(const bf16x8*)&lds[a1 + 4096 + 2048];                          \
        if (SP01) { GLL(xbc + sA1 + voffA, DAK1(PAR));                            \
                    GLL(xbc + sA1 + voffA + CJA_B, DAK1(PAR) + 8192); }           \
        sA1 += ((TT) == 22 || (TT) == 46) ? 64640 : 128;                          \
        asm volatile("s_waitcnt lgkmcnt(4)" ::: "memory");                        \
        __builtin_amdgcn_sched_barrier(0);                                        \
        __builtin_amdgcn_s_setprio(1);                                            \
        MFMA8(afE, b0, 0);                                                        \
        __builtin_amdgcn_s_setprio(0);                                            \
        asm volatile("s_waitcnt " VMS ::: "memory");                              \
        __builtin_amdgcn_s_barrier();                                             \
        __builtin_amdgcn_sched_barrier(0);                                        \
        /* ---- p1: compute (kh0,mh1) afO,b0; prefetch afE<-(kh1,mh0)+b1; BK1 */  \
        afE[0] = *(const bf16x8*)&lds[a0 + 16384];                                \
        afE[1] = *(const bf16x8*)&lds[a1 + 16384];                                \
        afE[2] = *(const bf16x8*)&lds[a0 + 16384 + 2048];                         \
        afE[3] = *(const bf16x8*)&lds[a1 + 16384 + 2048];                         \
        b1[0] = *(const bf16x8*)&lds[c0 + 16384];                                 \
        b1[1] = *(const bf16x8*)&lds[c1 + 16384];                                 \
        b1[2] = *(const bf16x8*)&lds[c0 + 16384 + 2048];                          \
        b1[3] = *(const bf16x8*)&lds[c1 + 16384 + 2048];                          \
        if (SP01) { GLL(ebc + sB1 + voffB, DBK1(PAR));                            \
                    GLL(ebc + sB1 + voffB + CJB_B, DBK1(PAR) + 8192); }           \
        sB1 += (((TT) & 7) == 6) ? 1047680 : 128;                                 \
        asm volatile("s_waitcnt lgkmcnt(8)" ::: "memory");                        \
        __builtin_amdgcn_sched_barrier(0);                                        \
        __builtin_amdgcn_s_setprio(1);                                            \
        MFMA8(afO, b0, 1);                                                        \
        __builtin_amdgcn_s_setprio(0);                                            \
        __builtin_amdgcn_s_barrier();                                             \
        __builtin_amdgcn_sched_barrier(0);                                        \
        /* ---- p2: compute (kh1,mh0) afE,b1; prefetch afO<-(kh1,mh1); stage AK0 */\
        afO[0] = *(const bf16x8*)&lds[a0 + 16384 + 4096];                         \
        afO[1] = *(const bf16x8*)&lds[a1 + 16384 + 4096];                         \
        afO[2] = *(const bf16x8*)&lds[a0 + 16384 + 4096 + 2048];                  \
        afO[3] = *(const bf16x8*)&lds[a1 + 16384 + 4096 + 2048];                  \
        if (SP23) { GLL(xbc + sA0 + voffA, DAK0(PAR));                            \
                    GLL(xbc + sA0 + voffA + CJA_B, DAK0(PAR) + 8192); }           \
        sA0 += ((TT) == 21 || (TT) == 45) ? 64640 : 128;                          \
        asm volatile("s_waitcnt lgkmcnt(4)" ::: "memory");                        \
        __builtin_amdgcn_sched_barrier(0);                                        \
        __builtin_amdgcn_s_setprio(1);                                            \
        MFMA8(afE, b1, 0);                                                        \
        __builtin_amdgcn_s_setprio(0);                                            \
        asm volatile("s_waitcnt " VMS ::: "memory");                              \
        __builtin_amdgcn_s_barrier();                                             \
        __builtin_amdgcn_sched_barrier(0);                                        \
        /* ---- p3: compute (kh1,mh1) afO,b1; prefetch next tile afE,b0; BK0 */   \
        if (!(LAST)) {                                                            \
            const int na0 = (PAR) ? aOffE0 : aOffO0;                              \
            const int na1 = (PAR) ? aOffE1 : aOffO1;                              \
            const int nc0 = (PAR) ? bOffE0 : bOffO0;                              \
            const int nc1 = (PAR) ? bOffE1 : bOffO1;                              \
            afE[0] = *(const bf16x8*)&lds[na0];                                   \
            afE[1] = *(const bf16x8*)&lds[na1];                                   \
            afE[2] = *(const bf16x8*)&lds[na0 + 2048];                            \
            afE[3] = *(const bf16x8*)&lds[na1 + 2048];                            \
            b0[0] = *(const bf16x8*)&lds[nc0];                                    \
            b0[1] = *(const bf16x8*)&lds[nc1];                                    \
            b0[2] = *(const bf16x8*)&lds[nc0 + 2048];                             \
            b0[3] = *(const bf16x8*)&lds[nc1 + 2048];                             \
        }                                                                         \
        if (SP23) { GLL(ebc + sB0 + voffB, DBK0(PAR));                            \
                    GLL(ebc + sB0 + voffB + CJB_B, DBK0(PAR) + 8192); }           \
        sB0 += (((TT) & 7) == 5) ? 1047680 : 128;                                 \
        asm volatile("s_waitcnt " LGK3 ::: "memory");                             \
        __builtin_amdgcn_sched_barrier(0);                                        \
        __builtin_amdgcn_s_setprio(1);                                            \
        MFMA8(afO, b1, 1);                                                        \
        __builtin_amdgcn_s_setprio(0);                                            \
        __builtin_amdgcn_s_barrier();                                             \
        __builtin_amdgcn_sched_barrier(0);                                        \
    }

// ---------------- 256x256 pipelined 32x32x16-MFMA implicit-GEMM conv ----------------
__global__ __launch_bounds__(512, 2) void mfma_conv8_kernel(
    const __hip_bfloat16* __restrict__ xbf, const __hip_bfloat16* __restrict__ ebf,
    const float* __restrict__ bias, float* __restrict__ out) {
    __shared__ __align__(16) char lds[131072];

    const int tid = threadIdx.x;
    const int lane = tid & 63;
    const int wid = tid >> 6;      // 0..7
    const int wy = wid >> 2;       // 0..1 : M half (128 rows)
    const int wx = wid & 3;        // 0..3 : N quarter (64 cols)

    const int bid = blockIdx.x;
    const int wkid = ((bid & 7) << 7) + (bid >> 3);
    const int mtile = wkid >> 2;
    const int ntile = wkid & 3;
    const int n = mtile >> 4;
    const int sub = mtile & 15;
    const int qh0 = (sub >> 2) << 4;
    const int qw0 = (sub & 3) << 4;
    const int n0 = ntile << 8;

    const int qc_s = lane >> 2;
    // write-side swizzle: wkey(row) = r2 + 2*r1 (row = lane>>2 -> r1=(lane>>3)&1, r2=(lane>>4)&1)
    const int src_slot = (((lane & 3) ^ (((lane >> 4) & 1) + 2 * ((lane >> 3) & 1))) << 3);

    f32x16 acc[8];
#pragma unroll
    for (int j = 0; j < 8; ++j) acc[j] = (f32x16)(0.f);

    char* ldsW = lds + (wid << 10);
    const char* xbc = (const char*)xbf;
    const char* ebc = (const char*)ebf;

    // prologue-only generic stage (full address computation; runs 6 times)
    auto stage = [&](int s) {
        const int tt2 = s >> 2;
        const int part = s & 3;
        const int mat = part & 1;
        const int kh = part >> 1;
        const int tap = tt2 >> 3;
        const int chan = ((tt2 & 7) << 6) + (kh << 5) + src_slot;
        char* dst = lds + ((((tt2 & 1) << 2) | (mat << 1) | kh) << 14) + (wid << 10);
        if (mat == 0) {
            const int fi = (tap * 171) >> 9;
            const int fj = tap - fi * 3;
            const int wp = qw0 + fj + qc_s;
#pragma unroll
            for (int c = 0; c < 2; ++c) {
                const int hp = qh0 + fi + (c << 3) + wid;
                const __hip_bfloat16* src =
                    xbf + (((size_t)n * HP + hp) * HP + wp) * IN_CH + chan;
                __builtin_amdgcn_global_load_lds(
                    (const __attribute__((address_space(1))) unsigned int*)src,
                    (__attribute__((address_space(3))) unsigned int*)(dst + (c << 13)),
                    16, 0, 0);
            }
        } else {
#pragma unroll
            for (int c = 0; c < 2; ++c) {
                const int r = (c << 7) + (wid << 4) + qc_s;
                const __hip_bfloat16* src =
                    ebf + ((size_t)tap * 1024 + n0 + r) * IN_CH + chan;
                __builtin_amdgcn_global_load_lds(
                    (const __attribute__((address_space(1))) unsigned int*)src,
                    (__attribute__((address_space(3))) unsigned int*)(dst + (c << 13)),
                    16, 0, 0);
            }
        }
    };

    // read-side: row = lane&31 -> key = r2 + 2*r1 = ((lane>>2)&1) + 2*((lane>>1)&1)
    const int key = ((lane >> 2) & 1) + 2 * ((lane >> 1) & 1);
    const int sl = lane >> 5;
    const int arow = ((wy << 7) + (lane & 31)) * 64;
    const int aOffE0 = arow + ((sl ^ key) << 4);
    const int aOffE1 = arow + (((sl | 2) ^ key) << 4);
    const int aOffO0 = aOffE0 + 65536;
    const int aOffO1 = aOffE1 + 65536;
    const int brow = 32768 + ((wx << 6) + (lane & 31)) * 64;
    const int bOffE0 = brow + ((sl ^ key) << 4);
    const int bOffE1 = brow + (((sl | 2) ^ key) << 4);
    const int bOffO0 = bOffE0 + 65536;
    const int bOffO1 = bOffE1 + 65536;

    // staging: uniform scalar byte offsets + per-lane 32-bit voffsets
    const int voffA = ((((n * HP + qh0 + wid) * HP + qw0 + qc_s) * IN_CH) + src_slot) * 2;
    const int voffB = (((n0 + (wid << 4) + qc_s) * IN_CH) + src_slot) * 2;
    int sA1 = 192, sA0 = 256, sB1 = 192, sB0 = 256;  // bytes (96/128 elements)

    // ---- prologue: items 0..5; confirm items 0,1; read phase-0 frags ----
#pragma unroll
    for (int s = 0; s < 6; ++s) stage(s);
    asm volatile("s_waitcnt vmcnt(8)" ::: "memory");
    __builtin_amdgcn_s_barrier();
    __builtin_amdgcn_sched_barrier(0);

    bf16x8 afE[4], afO[4], b0[4], b1[4];
    afE[0] = *(const bf16x8*)&lds[aOffE0];
    afE[1] = *(const bf16x8*)&lds[aOffE1];
    afE[2] = *(const bf16x8*)&lds[aOffE0 + 2048];
    afE[3] = *(const bf16x8*)&lds[aOffE1 + 2048];
    b0[0] = *(const bf16x8*)&lds[bOffE0];
    b0[1] = *(const bf16x8*)&lds[bOffE1];
    b0[2] = *(const bf16x8*)&lds[bOffE0 + 2048];
    b0[3] = *(const bf16x8*)&lds[bOffE1 + 2048];

    // ---- main loop: tiles 0..67, then peeled tail 68..71 ----
#pragma unroll 1
    for (int tt = 0; tt < 68; tt += 2) {
        TILE_ITER(0, tt, 1, 1, "vmcnt(6)", "lgkmcnt(8)", 0);
        TILE_ITER(1, tt + 1, 1, 1, "vmcnt(6)", "lgkmcnt(8)", 0);
    }
    TILE_ITER(0, 68, 1, 1, "vmcnt(6)", "lgkmcnt(8)", 0);
    TILE_ITER(1, 69, 1, 1, "vmcnt(0)", "lgkmcnt(8)", 0);
    TILE_ITER(0, 70, 1, 0, "vmcnt(0)", "lgkmcnt(8)", 0);
    TILE_ITER(1, 71, 0, 0, "vmcnt(0)", "lgkmcnt(0)", 1);

    // ---- epilogue: bias + leaky-relu*sqrt2 + clamp, scatter to NCHW ----
    // C layout (m74/m101): col = lane&31, row = (reg&3) + 8*(reg>>2) + 4*(lane>>5)
    float bv[2];
#pragma unroll
    for (int nt = 0; nt < 2; ++nt)
        bv[nt] = bias[(n0 + (wx << 6) + (nt << 5) + (lane & 31)) >> 2];
#pragma unroll
    for (int j = 0; j < 8; ++j) {
        const int mt = j >> 1, nt = j & 1;
        const int nn = n0 + (wx << 6) + (nt << 5) + (lane & 31);
        const int oc = nn >> 2, pu = (nn >> 1) & 1, pv = nn & 1;
#pragma unroll
        for (int v = 0; v < 16; ++v) {
            const int m = (wy << 7) + (mt << 5) + (v & 3) + ((v >> 2) << 3) + (sl << 2);
            const int qr = m >> 4, qc = m & 15;
            const int hb = 2 * (qh0 + qr), wb = 2 * (qw0 + qc);
            float val = acc[j][v] + bv[nt];
            val = (val >= 0.f ? val : 0.2f * val) * ACT_GAIN;
            val = fminf(fmaxf(val, -CLAMP_V), CLAMP_V);
            out[(((size_t)n * OUT_CH + oc) * HOUT + (hb + pu)) * HOUT + (wb + pv)] = val;
        }
    }
}

// ---------------- fallback (R1 proven path) if workspace too small ----------------
__global__ void build_e_kernel(const float* __restrict__ w, float* __restrict__ e_ws) {
    int gid = blockIdx.x * blockDim.x + threadIdx.x;
    if (gid >= OUT_CH * IN_CH) return;
    float wm[3][3];
    const float* wp = w + (size_t)gid * 9;
#pragma unroll
    for (int a = 0; a < 3; ++a)
#pragma unroll
        for (int b = 0; b < 3; ++b) wm[a][b] = wp[a * 3 + b] * WSCALE;
    float* op = e_ws + (size_t)gid * 36;
#pragma unroll
    for (int i = 0; i < 3; ++i)
#pragma unroll
        for (int j = 0; j < 3; ++j)
#pragma unroll
            for (int pu = 0; pu < 2; ++pu)
#pragma unroll
                for (int pv = 0; pv < 2; ++pv) {
                    float s = 0.f;
#pragma unroll
                    for (int a = 0; a < 3; ++a)
#pragma unroll
                        for (int b = 0; b < 3; ++b)
                            s += wm[a][b] * c_G[pu][i][a] * c_G[pv][j][b];
                    op[(i * 3 + j) * 4 + pu * 2 + pv] = s;
                }
}

#define OGB 8
#define CB 8
#define QT 16
__global__ __launch_bounds__(256) void fused_conv_kernel(
    const float* __restrict__ x, const float* __restrict__ e_ws,
    const float* __restrict__ bias, float* __restrict__ out) {
    __shared__ float sX[CB][18][19];
    __shared__ float4 sE[OGB * CB * 9];
    const int tid = threadIdx.x;
    const int o2 = tid >> 7;
    const int qy = (tid >> 3) & 15;
    const int qxp = tid & 7;
    const int tileIdx = blockIdx.x;
    const int hq0 = (tileIdx >> 2) * QT;
    const int wq0 = (tileIdx & 3) * QT;
    const int o0 = blockIdx.y * OGB;
    const int n = blockIdx.z;
    float4 acc[2][4];
#pragma unroll
    for (int q = 0; q < 2; ++q)
#pragma unroll
        for (int oo = 0; oo < 4; ++oo) acc[q][oo] = make_float4(0.f, 0.f, 0.f, 0.f);
    for (int c0 = 0; c0 < IN_CH; c0 += CB) {
        for (int idx = tid; idx < CB * 18 * 18; idx += 256) {
            int cc = idx / 324;
            int rem = idx - cc * 324;
            int r = rem / 18;
            int col = rem - r * 18;
            int h = hq0 - 1 + r;
            int ww = wq0 - 1 + col;
            float v = 0.f;
            if (h >= 0 && h < HIN && ww >= 0 && ww < HIN)
                v = x[(((size_t)n * IN_CH + (c0 + cc)) * HIN + h) * HIN + ww];
            sX[cc][r][col] = v;
        }
        {
            float* sEf = (float*)sE;
            for (int idx = tid; idx < OGB * CB * 36; idx += 256) {
                int ol = idx / (CB * 36);
                int rem = idx - ol * (CB * 36);
                sEf[ol * (CB * 36) + rem] =
                    e_ws[((size_t)(o0 + ol) * IN_CH + c0) * 36 + rem];
            }
        }
        __syncthreads();
#pragma unroll 1
        for (int cc = 0; cc < CB; ++cc) {
#pragma unroll
            for (int i = 0; i < 3; ++i) {
#pragma unroll
                for (int j = 0; j < 3; ++j) {
                    float xv0 = sX[cc][qy + i][2 * qxp + j];
                    float xv1 = sX[cc][qy + i][2 * qxp + 1 + j];
#pragma unroll
                    for (int oo = 0; oo < 4; ++oo) {
                        float4 e = sE[((o2 * 4 + oo) * CB + cc) * 9 + i * 3 + j];
                        acc[0][oo].x += xv0 * e.x; acc[0][oo].y += xv0 * e.y;
                        acc[0][oo].z += xv0 * e.z; acc[0][oo].w += xv0 * e.w;
                        acc[1][oo].x += xv1 * e.x; acc[1][oo].y += xv1 * e.y;
                        acc[1][oo].z += xv1 * e.z; acc[1][oo].w += xv1 * e.w;
                    }
                }
            }
        }
        __syncthreads();
    }
#pragma unroll
    for (int q = 0; q < 2; ++q) {
        int qx = 2 * qxp + q;
        int u0 = 2 * (hq0 + qy);
        int v0 = 2 * (wq0 + qx);
#pragma unroll
        for (int oo = 0; oo < 4; ++oo) {
            int o = o0 + o2 * 4 + oo;
            float b = bias[o];
            float vals[4] = {acc[q][oo].x, acc[q][oo].y, acc[q][oo].z, acc[q][oo].w};
#pragma unroll
            for (int p = 0; p < 4; ++p) {
                int pu = p >> 1, pv = p & 1;
                float v = vals[p] + b;
                v = (v >= 0.f ? v : 0.2f * v) * ACT_GAIN;
                v = fminf(fmaxf(v, -CLAMP_V), CLAMP_V);
                out[(((size_t)n * OUT_CH + o) * HOUT + (u0 + pu)) * HOUT + (v0 + pv)] = v;
            }
        }
    }
}

extern "C" void kernel_launch(void* const* d_in, const int* in_sizes, int n_in,
                              void* d_out, int out_size, void* d_ws, size_t ws_size,
                              hipStream_t stream) {
    const float* x = (const float*)d_in[0];
    const float* w = (const float*)d_in[1];
    const float* bias = (const float*)d_in[2];
    float* out = (float*)d_out;

    if (ws_size >= WS_NEED) {
        __hip_bfloat16* xbf = (__hip_bfloat16*)d_ws;
        __hip_bfloat16* ebf = (__hip_bfloat16*)((char*)d_ws + XBF_BYTES);
        xpose_kernel<<<dim3(8, HP, NIMG), 256, 0, stream>>>(x, xbf);
        build_ebf_kernel<<<(OUT_CH * IN_CH + 255) / 256, 256, 0, stream>>>(w, ebf);
        mfma_conv8_kernel<<<dim3(1024), 512, 0, stream>>>(xbf, ebf, bias, out);
    } else {
        float* e_ws = (float*)d_ws;
        build_e_kernel<<<(OUT_CH * IN_CH + 255) / 256, 256, 0, stream>>>(w, e_ws);
        dim3 grid(16, OUT_CH / OGB, NIMG);
        fused_conv_kernel<<<grid, 256, 0, stream>>>(x, e_ws, bias, out);
    }
}